// Round 8
// baseline (260.233 us; speedup 1.0000x reference)
//
#include <hip/hip_runtime.h>
#include <hip/hip_bf16.h>

#define B_    4
#define N_    16384
#define K_    16
#define CIN_  64
#define CF_   67          // 3 + 64 concat channels
#define COUT_ 128
#define AGGP2 1152        // lwb row length: 36 k-steps * 32 (pad 1088..1151 = 0)
#define P_    16          // points per block
#define FSTR  72          // bf16 ft record stride in shorts (144 B)
#define FTS   1096        // FT per-point stride in shorts (union region)
#define WTS   272         // s_WT point stride in shorts
#define NEG_  0.1f

typedef __attribute__((ext_vector_type(8))) short short8;
typedef __attribute__((ext_vector_type(4))) float f32x4;
typedef __attribute__((ext_vector_type(2))) unsigned int uint2_t;
typedef __attribute__((ext_vector_type(4))) unsigned int uint4_t;

__device__ __forceinline__ unsigned short f2b(float f) {
    __hip_bfloat16 h = __float2bfloat16(f);
    return *reinterpret_cast<unsigned short*>(&h);
}
__device__ __forceinline__ float leaky(float x) { return x >= 0.f ? x : NEG_ * x; }

// ---------------------------------------------------------------------------
// Kernel 1 (fused prep):
//  blocks [0,1024):   transpose concat(xyz,features) -> ft bf16 [B][N][FSTR]
//  blocks [1024,1152): lin_w fp32 -> lwb bf16 [128][AGGP2], flat kappa = w*68+c
//                      (c=67 and kappa>=1088 zeroed)
// ---------------------------------------------------------------------------
__global__ __launch_bounds__(256) void pc_prep(
    const float* __restrict__ xyz,
    const float* __restrict__ feats,
    const float* __restrict__ lin_w,
    unsigned short* __restrict__ ft,
    short* __restrict__ lwb)
{
    const int bid = blockIdx.x, t = threadIdx.x;
    if (bid < 1024) {
        __shared__ float st[64][68];           // [j_local][c]
        const int b  = bid >> 8;
        const int j0 = (bid & 255) << 6;
        const int jl = t & 63, cs = t >> 6;
        for (int c = cs; c < 68; c += 4) {
            float v = 0.f;
            if (c < 3)        v = xyz  [((size_t)b * 3    + c)       * N_ + j0 + jl];
            else if (c < CF_) v = feats[((size_t)b * CIN_ + (c - 3)) * N_ + j0 + jl];
            st[jl][c] = v;
        }
        __syncthreads();
        unsigned int* outp = (unsigned int*)(ft + (size_t)(b * N_ + j0) * FSTR);
        for (int idx = t; idx < 64 * 36; idx += 256) {   // 36 uints per record
            const int j2 = idx / 36, cu = idx % 36;
            const int c0 = cu * 2, c1 = c0 + 1;
            const unsigned lo = (c0 < CF_) ? (unsigned)f2b(st[j2][c0]) : 0u;
            const unsigned hi = (c1 < CF_) ? (unsigned)f2b(st[j2][c1]) : 0u;
            outp[idx] = lo | (hi << 16);
        }
    } else {
        const int o = bid - 1024;              // 128 out-channel rows
        const float* src = lin_w + (size_t)o * (16 * CF_);
        short*       dst = lwb   + (size_t)o * AGGP2;
        for (int i = t; i < AGGP2; i += 256) {
            short v = 0;
            if (i < 1088) {
                const int w = i / 68, c = i % 68;
                if (c < CF_) v = (short)f2b(src[w * CF_ + c]);
            }
            dst[i] = v;
        }
    }
}

// ---------------------------------------------------------------------------
// Kernel 2: fused weight-net MLP + pair-MFMA agg + pipelined MFMA linear.
// s_mem union: FT[p][c][k] (phases 1-2b reads) then frag-linear B (phase 3):
//   entry(ksq in [0,144), n in [0,16)) at shorts ksq*128 + ((n+ksq)&15)*8,
//   holding B[k=8*ksq..+7][n]  (flat k kappa = w*68+c; entries 136..143 = 0).
// Barrier #1 between FT reads and frag stores (D crosses in registers);
// barrier #2 before phase 3. Phase 3: 9 chunks of 4 k-steps, double-buffered
// A-loads (8 x 16B in flight) hide L2 latency; B reads are canonical
// contiguous ds_read_b128 (bank-even).
// ---------------------------------------------------------------------------
__global__ __launch_bounds__(256, 2) void pc_main(
    const float*          __restrict__ xyz,
    const unsigned short* __restrict__ ft,
    const int*            __restrict__ knn,
    const float* __restrict__ w1, const float* __restrict__ b1,
    const float* __restrict__ w2, const float* __restrict__ b2,
    const short* __restrict__ lwb, const float* __restrict__ lin_b,
    float* __restrict__ out)
{
    __shared__ __align__(16) short s_mem[18432];       // 36864 B union
    __shared__ __align__(16) short s_WT[P_ * WTS];     // [p][w*16+k] bf16, 8704 B
    __shared__ int s_idx[P_ * K_];                     // 1 KB

    const int t   = threadIdx.x;
    const int bid = blockIdx.x;            // 4096
    const int b   = bid >> 10;
    const int n0  = (bid & 1023) << 4;
    const unsigned short* ftb = ft + (size_t)b * N_ * FSTR;

    // ---------------- phase 1: weight-net MLP, one thread per (p,k) --------
    {
        const int p = t >> 4, k = t & 15;
        const int n = n0 + p;
        const int j = knn[((size_t)(b * N_ + n)) * K_ + k];
        s_idx[p * K_ + k] = j;
        const float* xb = xyz + (size_t)b * 3 * N_;   // fp32-exact MLP input
        const float dx0 = xb[j]          - xb[n];
        const float dx1 = xb[N_ + j]     - xb[N_ + n];
        const float dx2 = xb[2 * N_ + j] - xb[2 * N_ + n];
        float h[8];
#pragma unroll
        for (int i = 0; i < 8; i++)
            h[i] = leaky(b1[i] + w1[i*3+0]*dx0 + w1[i*3+1]*dx1 + w1[i*3+2]*dx2);
        short* wd = s_WT + p * WTS + k;               // WT[p][w][k], stride 16
#pragma unroll
        for (int w = 0; w < 16; w++) {
            float a = b2[w];
#pragma unroll
            for (int i = 0; i < 8; i++) a += w2[w*8+i] * h[i];
            wd[w * 16] = (short)f2b(leaky(a));
        }
    }
    __asm__ __volatile__("" ::: "memory");   // wave-local: DS pipe in-order

    // ---------------- phase 2a: gather + register transpose -> FT[c][k] ----
    {
        const int p = t >> 4, s = t & 15;
        const int* ip = s_idx + p * K_;
        const bool tl = (s < 3);
        uint2_t fb[K_];
        unsigned feu[8] = {0,0,0,0,0,0,0,0};
#pragma unroll
        for (int k = 0; k < K_; k++) {
            const unsigned short* rec = ftb + (size_t)ip[k] * FSTR;
            fb[k] = *(const uint2_t*)(rec + 4 * s);
            if (tl) feu[k >> 1] |= ((unsigned)rec[64 + s]) << (16 * (k & 1));
        }
        short* frow = s_mem + p * FTS;
#pragma unroll
        for (int i = 0; i < 4; i++) {        // rows c = 4s+i, k-contiguous
            const unsigned sel = (i & 1) ? 0x07060302u : 0x05040100u;
            unsigned pk[8];
#pragma unroll
            for (int d = 0; d < 8; d++) {
                const unsigned lo = (i < 2) ? fb[2*d].x   : fb[2*d].y;
                const unsigned hi = (i < 2) ? fb[2*d+1].x : fb[2*d+1].y;
                pk[d] = __builtin_amdgcn_perm(hi, lo, sel);
            }
            const int c = 4 * s + i;
            uint4_t q0 = { pk[0], pk[1], pk[2], pk[3] };
            uint4_t q1 = { pk[4], pk[5], pk[6], pk[7] };
            *(uint4_t*)(frow + c * 16)     = q0;
            *(uint4_t*)(frow + c * 16 + 8) = q1;
        }
        if (tl) {                            // tail rows c = 64..66
            uint4_t q0 = { feu[0], feu[1], feu[2], feu[3] };
            uint4_t q1 = { feu[4], feu[5], feu[6], feu[7] };
            *(uint4_t*)(frow + (64 + s) * 16)     = q0;
            *(uint4_t*)(frow + (64 + s) * 16 + 8) = q1;
        }
        if (s == 3) {                        // row 67 = zero -> agg[w][67] = 0
            uint4_t z = {0u, 0u, 0u, 0u};
            *(uint4_t*)(frow + 67 * 16)     = z;
            *(uint4_t*)(frow + 67 * 16 + 8) = z;
        }
    }
    __asm__ __volatile__("" ::: "memory");

    // ---------------- phase 2b: pair MFMA agg -> frag-linear B -------------
    {
        const int lane = t & 63;
        const int wq   = lane >> 4;          // quad
        const int pr   = lane & 15;
        const int pb   = (t >> 6) * 4;       // wave's first point
        const int kh   = (wq & 1) * 8;       // k-halfword within a point
        const int side = (wq < 2) ? 0 : 1;   // B-operand / D-row point select
        const int asid = (pr < 8) ? 0 : 1;   // A-operand point select
        const bool act = (side == asid);
        const int cq   = 4 * (wq & 1);
        const int bq   = (68 * pr + cq) >> 3;   // base entry index (per w=pr)
        const int rem  = (68 * pr + cq) & 7;    // j-offset within entry {0,4}
        uint2_t pk[2][9];
#pragma unroll
        for (int pair = 0; pair < 2; pair++) {
            const int pA = pb + 2 * pair;
            const short8 bfr = *(const short8*)(s_WT + (pA + side) * WTS + pr * 16 + kh);
            const short* ap  = s_mem + (size_t)(pA + asid) * FTS + (pr & 7) * 16 + kh;
#pragma unroll
            for (int cc = 0; cc < 9; cc++) {
                short8 af = {0,0,0,0,0,0,0,0};
                if (act && (cc < 8 || (pr & 7) < 4))
                    af = *(const short8*)(ap + 128 * cc);
                const f32x4 D = __builtin_amdgcn_mfma_f32_16x16x32_bf16(
                                    af, bfr, (f32x4){0.f,0.f,0.f,0.f}, 0, 0, 0);
                pk[pair][cc].x = (unsigned)f2b(D.x) | ((unsigned)f2b(D.y) << 16);
                pk[pair][cc].y = (unsigned)f2b(D.z) | ((unsigned)f2b(D.w) << 16);
            }
        }
        __syncthreads();        // all FT/WT reads complete before frag stores
#pragma unroll
        for (int pair = 0; pair < 2; pair++) {
            const int p = pb + 2 * pair + side;
#pragma unroll
            for (int cc = 0; cc < 9; cc++) {
                if (cc == 8 && cq == 4) continue;   // c=68..71 don't exist
                const int ksq = bq + cc;
                *(uint2_t*)(s_mem + ksq * 128 + ((p + ksq) & 15) * 8 + rem)
                    = pk[pair][cc];
            }
        }
        // zero tail entries ksq 136..143 (k-steps 34,35)
        *(uint2_t*)(s_mem + 17408 + 4 * t) = (uint2_t){0u, 0u};
    }
    __syncthreads();

    // ---------------- phase 3: out[128 x 16] = L[128x1152] @ Bfrag ---------
    {
        const int lane = t & 63, wid = t >> 6;
        const int quad = lane >> 4, pr = lane & 15;
        // A fragment: lane holds A[m=pr][k=quad*8+j]; A row = out channel
        const short* aR0 = lwb + (size_t)(wid * 32 + pr) * AGGP2 + 8 * quad;
        const short* aR1 = aR0 + 16 * AGGP2;
        // B fragment offsets within a chunk (rotation is ch-invariant)
        int boff[4];
#pragma unroll
        for (int j = 0; j < 4; j++)
            boff[j] = ((4 * j + quad) * 16 + ((pr + quad + 4 * j) & 15)) * 8;

        f32x4 acc0 = {0.f, 0.f, 0.f, 0.f};
        f32x4 acc1 = {0.f, 0.f, 0.f, 0.f};
        short8 A0[4], A1[4], N0[4], N1[4];
#pragma unroll
        for (int j = 0; j < 4; j++) {
            A0[j] = *(const short8*)(aR0 + 32 * j);
            A1[j] = *(const short8*)(aR1 + 32 * j);
        }
        for (int ch = 0; ch < 9; ch++) {
            if (ch < 8) {
                const short* an0 = aR0 + 128 * (ch + 1);
                const short* an1 = aR1 + 128 * (ch + 1);
#pragma unroll
                for (int j = 0; j < 4; j++) {
                    N0[j] = *(const short8*)(an0 + 32 * j);
                    N1[j] = *(const short8*)(an1 + 32 * j);
                }
            }
            const short* bb = s_mem + 2048 * ch;
#pragma unroll
            for (int j = 0; j < 4; j++) {
                const short8 bfr = *(const short8*)(bb + boff[j]);
                acc0 = __builtin_amdgcn_mfma_f32_16x16x32_bf16(A0[j], bfr, acc0, 0, 0, 0);
                acc1 = __builtin_amdgcn_mfma_f32_16x16x32_bf16(A1[j], bfr, acc1, 0, 0, 0);
            }
#pragma unroll
            for (int j = 0; j < 4; j++) { A0[j] = N0[j]; A1[j] = N1[j]; }
        }
        // epilogue: D row = quad*4 + r (out channel within tile), D col = pr
        const int o0 = wid * 32 + quad * 4;
#pragma unroll
        for (int r = 0; r < 4; r++) {
            const int oA = o0 + r;
            const int oB = oA + 16;
            const float vA = leaky(acc0[r] + lin_b[oA]);
            const float vB = leaky(acc1[r] + lin_b[oB]);
            out[((size_t)(b * COUT_ + oA)) * N_ + n0 + pr] = vA;
            out[((size_t)(b * COUT_ + oB)) * N_ + n0 + pr] = vB;
        }
    }
}

extern "C" void kernel_launch(void* const* d_in, const int* in_sizes, int n_in,
                              void* d_out, int out_size, void* d_ws, size_t ws_size,
                              hipStream_t stream)
{
    const float* xyz   = (const float*)d_in[0];
    const float* feats = (const float*)d_in[1];
    const int*   knn   = (const int*)d_in[2];
    const float* w1    = (const float*)d_in[3];
    const float* b1    = (const float*)d_in[4];
    const float* w2    = (const float*)d_in[5];
    const float* b2    = (const float*)d_in[6];
    const float* lin_w = (const float*)d_in[7];
    const float* lin_b = (const float*)d_in[8];
    float* out = (float*)d_out;

    unsigned short* ft = (unsigned short*)d_ws;              // 9.44 MB bf16
    short* lwb = (short*)((char*)d_ws + (size_t)B_ * N_ * FSTR * sizeof(short));
                                                             // 128*1152*2 = 295 KB

    hipLaunchKernelGGL(pc_prep, dim3(1024 + COUT_), dim3(256), 0, stream,
                       xyz, feats, lin_w, ft, lwb);
    hipLaunchKernelGGL(pc_main, dim3(B_ * (N_ / P_)), dim3(256), 0, stream,
                       xyz, ft, knn, w1, b1, w2, b2, lwb, lin_b, out);
}